// Round 16
// baseline (241.327 us; speedup 1.0000x reference)
//
#include <hip/hip_runtime.h>

#define SEQ 4096
#define CDIM 512
#define HID 512
#define NB 2
#define NHEADS 8

typedef float f32x4 __attribute__((ext_vector_type(4)));
typedef short bf16x8 __attribute__((ext_vector_type(8)));

static __device__ __forceinline__ short f2bf(float f) {
  unsigned u = __float_as_uint(f);
  u = (u + 0x7fffu + ((u >> 16) & 1u)) >> 16;
  return (short)u;
}
static __device__ __forceinline__ float bf2f(short h) {
  return __uint_as_float(((unsigned)(unsigned short)h) << 16);
}
static __device__ __forceinline__ unsigned pk2bf(float a, float b) {
  unsigned r;
  asm("v_cvt_pk_bf16_f32 %0, %1, %2" : "=v"(r) : "v"(a), "v"(b));
  return r;
}
// async global->LDS, 16B per lane; LDS dest = wave-uniform base + lane*16
typedef const __attribute__((address_space(1))) char gas_char;
typedef __attribute__((address_space(3))) char las_char;
static __device__ __forceinline__ void gll16(const char* g, char* l) {
  __builtin_amdgcn_global_load_lds((gas_char*)g, (las_char*)l, 16, 0, 0);
}

// ---------------------------------------------------------------------------
// prep_w: fp32 weights -> bf16 hi/lo splits, plus collapsed biases (z=7).
// z=0: Wi NON-transposed [k][n]; z=1: Wc NON-transposed [k][n]
// z=2..6: Wq (x0.125*log2e), Wk, Wv, Wo1, Wo2 transposed [n][k]
// z=7: blocks (0..2, y==0) compute bq=(bi@Wq)*s, bk=bc@Wk, bv=bc@Wv.
// ---------------------------------------------------------------------------
__global__ __launch_bounds__(256) void prep_w(
    const float* Wi, const float* Wc, const float* Wq, const float* Wk,
    const float* Wv, const float* Wo1, const float* Wo2,
    const float* bi, const float* bc,
    unsigned short* wth, unsigned short* wtl, float* bqkv) {
  __shared__ float tile[32][33];
  const int z = blockIdx.z;
  const int tx = threadIdx.x, ty = threadIdx.y;
  if (z == 7) {
    if (blockIdx.y != 0 || blockIdx.x >= 3) return;
    const int zz = blockIdx.x;
    const float* b = (zz == 0) ? bi : bc;
    const float* W = (zz == 0) ? Wq : (zz == 1) ? Wk : Wv;
    const float s = (zz == 0) ? 0.18033688011112042f : 1.0f;
    const int tid = tx + ty * 32;
    for (int n = tid; n < 512; n += 256) {
      float acc = 0.0f;
#pragma unroll 8
      for (int k = 0; k < 512; ++k) acc += b[k] * W[k * 512 + n];
      bqkv[zz * 512 + n] = acc * s;
    }
    return;
  }
  const float* src;
  float scale = 1.0f;
  switch (z) {
    case 0: src = Wi; break;
    case 1: src = Wc; break;
    case 2: src = Wq; scale = 0.18033688011112042f; break;  // 0.125*log2(e)
    case 3: src = Wk; break;
    case 4: src = Wv; break;
    case 5: src = Wo1; break;
    default: src = Wo2; break;
  }
  const int n0 = blockIdx.x * 32, k0 = blockIdx.y * 32;
  for (int i = ty; i < 32; i += 8)
    tile[i][tx] = src[(k0 + i) * 512 + n0 + tx];
  __syncthreads();
  unsigned short* oh = wth + z * 262144;
  unsigned short* ol = wtl + z * 262144;
  if (z < 2) {
    for (int i = ty; i < 32; i += 8) {
      const float v = tile[i][tx];  // = W[k0+i][n0+tx]
      const short h = f2bf(v);
      oh[(k0 + i) * 512 + n0 + tx] = (unsigned short)h;
      ol[(k0 + i) * 512 + n0 + tx] = (unsigned short)f2bf(v - bf2f(h));
    }
  } else {
    for (int i = ty; i < 32; i += 8) {
      const float v = tile[tx][i] * scale;  // = W[k0+tx][n0+i]*scale
      const short h = f2bf(v);
      oh[(n0 + i) * 512 + k0 + tx] = (unsigned short)h;
      ol[(n0 + i) * 512 + k0 + tx] = (unsigned short)f2bf(v - bf2f(h));
    }
  }
}

// ---------------------------------------------------------------------------
// prep_x2: {x, ctx} [b][c][s] fp32 -> hi/lo planes [b][s][c] bf16 (one launch)
// ---------------------------------------------------------------------------
__global__ __launch_bounds__(256) void prep_x2(
    const float* __restrict__ x, const float* __restrict__ ctx,
    unsigned short* __restrict__ oh0, unsigned short* __restrict__ ol0,
    unsigned short* __restrict__ oh1, unsigned short* __restrict__ ol1) {
  __shared__ float tile[32][33];
  const int b = blockIdx.z & 1;
  const int ten = blockIdx.z >> 1;
  const float* in = ten ? ctx : x;
  unsigned short* oh = ten ? oh1 : oh0;
  unsigned short* ol = ten ? ol1 : ol0;
  const int s0 = blockIdx.x * 32, c0 = blockIdx.y * 32;
  const int tx = threadIdx.x, ty = threadIdx.y;
  const float* ib = in + (long)b * CDIM * SEQ;
  for (int i = ty; i < 32; i += 8)
    tile[i][tx] = ib[(long)(c0 + i) * SEQ + s0 + tx];
  __syncthreads();
  const long ob = (long)b * SEQ * CDIM;
  for (int i = ty; i < 32; i += 8) {
    const float v = tile[tx][i];
    const short h = f2bf(v);
    oh[ob + (long)(s0 + i) * CDIM + c0 + tx] = (unsigned short)h;
    ol[ob + (long)(s0 + i) * CDIM + c0 + tx] = (unsigned short)f2bf(v - bf2f(h));
  }
}

// ---------------------------------------------------------------------------
// Split-bf16 MFMA GEMM (R10 best-measured form), tile 128(M)x64(N), 4 waves,
// BK=32, double-buffered gll16 (pre-swizzled per-lane source, linear LDS dest).
// Loop: {sync(drains gll); issue gll next->buf^1; MFMA from buf}.
// Y = Ah*Wh + Ah*Wl + Al*Wh (fp32 acc). XCD-aware block swizzle.
// ---------------------------------------------------------------------------
#define OUT_DUAL 0
#define OUT_HI 1
#define OUT_F32 2

struct GemmJob {
  const unsigned short *Ah, *Al, *Wh, *Wl;
  const float* bias;
  void *outA, *outB;
  int tstore;
};

template <int OMODE, bool DO_GELU, bool HASB, int NJOBS, int GY, int NBATCH>
__global__ __launch_bounds__(256) void gemmN(GemmJob J0, GemmJob J1, GemmJob J2) {
  __shared__ __align__(16) char lds[49152];  // 2 x (16KB A + 8KB W)
  // XCD swizzle over grid dim3(8, GY, NBATCH*NJOBS)
  const int orig = blockIdx.x + ((blockIdx.y + blockIdx.z * GY) << 3);
  const int total = 8 * GY * NBATCH * NJOBS;
  const int work = (orig & 7) * (total >> 3) + (orig >> 3);
  const int bx = work & 7;
  const int rest = work >> 3;
  const int by = rest % GY;
  const int z = rest / GY;
  const int jz = z / NBATCH;
  const int bz = z % NBATCH;
  const GemmJob J = (NJOBS >= 3 && jz == 2) ? J2 : ((NJOBS >= 2 && jz == 1) ? J1 : J0);
  const int TS = J.tstore;
  const int t = threadIdx.x;
  const int lane = t & 63, wave = t >> 6;
  const int l15 = lane & 15, g = lane >> 4;
  const int m0 = by * 128, n0 = bx * 64;
  const long abase = (long)bz * SEQ * 512;

  const int grow = lane >> 3;                       // row within gll
  const int ch = (((lane & 7) << 4) ^ (grow << 4)); // swizzled byte in 128B row
  const int chp = ch & 63;                          // byte within 64B plane slice
  const char* pa = (const char*)((ch < 64) ? J.Ah : J.Al);
  const char* pw = (const char*)((ch < 64) ? J.Wh : J.Wl);
  const char* aG[4];
#pragma unroll
  for (int i = 0; i < 4; ++i)
    aG[i] = pa + ((abase + (long)(m0 + wave * 32 + i * 8 + grow) * 512) << 1) + chp;
  const char* wG[2];
#pragma unroll
  for (int i = 0; i < 2; ++i)
    wG[i] = pw + (((long)(n0 + wave * 16 + i * 8 + grow) * 512) << 1) + chp;

  f32x4 acc[4][2];
#pragma unroll
  for (int p = 0; p < 4; ++p)
#pragma unroll
    for (int q = 0; q < 2; ++q) acc[p][q] = (f32x4){0.f, 0.f, 0.f, 0.f};

  {
    char* LA = lds;
    char* LW = lds + 16384;
#pragma unroll
    for (int i = 0; i < 4; ++i) gll16(aG[i], LA + wave * 4096 + i * 1024);
#pragma unroll
    for (int i = 0; i < 2; ++i) gll16(wG[i], LW + wave * 2048 + i * 1024);
  }

  int buf = 0;
  for (int k0 = 0; k0 < 512; k0 += 32) {
    char* LA = lds + buf * 24576;
    char* LW = LA + 16384;
    __syncthreads();  // drains gll (vmcnt 0) + protects write-after-read
    if (k0 + 32 < 512) {
      char* NA = lds + (buf ^ 1) * 24576;
      char* NW = NA + 16384;
      const int koff = (k0 + 32) * 2;
#pragma unroll
      for (int i = 0; i < 4; ++i) gll16(aG[i] + koff, NA + wave * 4096 + i * 1024);
#pragma unroll
      for (int i = 0; i < 2; ++i) gll16(wG[i] + koff, NW + wave * 2048 + i * 1024);
    }

    if (!TS) {
      bf16x8 fbh[2], fbl[2];
#pragma unroll
      for (int q = 0; q < 2; ++q) {
        const int r = wave * 32 + q * 16 + l15;
        const char* rp = LA + r * 128;
        const int sw = (r & 7) << 4;
        fbh[q] = *(const bf16x8*)(rp + ((g << 4) ^ sw));
        fbl[q] = *(const bf16x8*)(rp + (((4 + g) << 4) ^ sw));
      }
#pragma unroll
      for (int p = 0; p < 4; ++p) {
        const int r = p * 16 + l15;
        const char* rp = LW + r * 128;
        const int sw = (r & 7) << 4;
        const bf16x8 fah = *(const bf16x8*)(rp + ((g << 4) ^ sw));
        const bf16x8 fal = *(const bf16x8*)(rp + (((4 + g) << 4) ^ sw));
#pragma unroll
        for (int q = 0; q < 2; ++q) {
          acc[p][q] = __builtin_amdgcn_mfma_f32_16x16x32_bf16(fah, fbh[q], acc[p][q], 0, 0, 0);
          acc[p][q] = __builtin_amdgcn_mfma_f32_16x16x32_bf16(fah, fbl[q], acc[p][q], 0, 0, 0);
          acc[p][q] = __builtin_amdgcn_mfma_f32_16x16x32_bf16(fal, fbh[q], acc[p][q], 0, 0, 0);
        }
      }
    } else {
      const int mB = (wave >> 1) * 64, nB = (wave & 1) * 32;
      bf16x8 fbh[2], fbl[2];
#pragma unroll
      for (int q = 0; q < 2; ++q) {
        const int r = nB + q * 16 + l15;
        const char* rp = LW + r * 128;
        const int sw = (r & 7) << 4;
        fbh[q] = *(const bf16x8*)(rp + ((g << 4) ^ sw));
        fbl[q] = *(const bf16x8*)(rp + (((4 + g) << 4) ^ sw));
      }
#pragma unroll
      for (int p = 0; p < 4; ++p) {
        const int r = mB + p * 16 + l15;
        const char* rp = LA + r * 128;
        const int sw = (r & 7) << 4;
        const bf16x8 fah = *(const bf16x8*)(rp + ((g << 4) ^ sw));
        const bf16x8 fal = *(const bf16x8*)(rp + (((4 + g) << 4) ^ sw));
#pragma unroll
        for (int q = 0; q < 2; ++q) {
          acc[p][q] = __builtin_amdgcn_mfma_f32_16x16x32_bf16(fah, fbh[q], acc[p][q], 0, 0, 0);
          acc[p][q] = __builtin_amdgcn_mfma_f32_16x16x32_bf16(fah, fbl[q], acc[p][q], 0, 0, 0);
          acc[p][q] = __builtin_amdgcn_mfma_f32_16x16x32_bf16(fal, fbh[q], acc[p][q], 0, 0, 0);
        }
      }
    }
    buf ^= 1;
  }

  const long obase = (long)bz * 512 * SEQ;
#pragma unroll
  for (int p = 0; p < 4; ++p)
#pragma unroll
    for (int q = 0; q < 2; ++q) {
      f32x4 v = acc[p][q];
      if (TS) {
        const int m = m0 + (wave >> 1) * 64 + p * 16 + 4 * g;  // vector spans m
        const int n = n0 + (wave & 1) * 32 + q * 16 + l15;
        if (HASB) {
          const float b = J.bias[n];
          v[0] += b; v[1] += b; v[2] += b; v[3] += b;
        }
        if (OMODE == OUT_F32) {
          float4 f;
          f.x = v[0]; f.y = v[1]; f.z = v[2]; f.w = v[3];
          *(float4*)((float*)J.outA + obase + (long)n * SEQ + m) = f;
        } else {
          const short4 h4 = make_short4(f2bf(v[0]), f2bf(v[1]), f2bf(v[2]), f2bf(v[3]));
          *(short4*)((unsigned short*)J.outA + obase + (long)n * SEQ + m) = h4;
        }
      } else {
        const int n = n0 + p * 16 + 4 * g;  // vector spans n
        const int m = m0 + wave * 32 + q * 16 + l15;
        if (HASB) v += *(const f32x4*)(J.bias + n);
        if (DO_GELU) {
#pragma unroll
          for (int r = 0; r < 4; ++r)
            v[r] = 0.5f * v[r] * (1.0f + erff(v[r] * 0.7071067811865476f));
        }
        unsigned short* oA = (unsigned short*)J.outA + obase + (long)m * 512 + n;
        if (OMODE == OUT_DUAL) {
          short h[4], l[4];
#pragma unroll
          for (int r = 0; r < 4; ++r) {
            h[r] = f2bf(v[r]);
            l[r] = f2bf(v[r] - bf2f(h[r]));
          }
          *(short4*)oA = make_short4(h[0], h[1], h[2], h[3]);
          *(short4*)((unsigned short*)J.outB + obase + (long)m * 512 + n) =
              make_short4(l[0], l[1], l[2], l[3]);
        } else {
          *(short4*)oA = make_short4(f2bf(v[0]), f2bf(v[1]), f2bf(v[2]), f2bf(v[3]));
        }
      }
    }
}

// ---------------------------------------------------------------------------
// Flash attention, bf16 MFMA (R10 best-measured form). 8 waves x 512 thr;
// QBLK=256 (2 x 16 q-rows per wave), KVBLK=64, gll16 2-buf staging,
// zero-shuffle exp2 softmax, MFMA row-sum, XCD swizzle.
// Q,K planes [b][s][512]; Vt [b][512 d][4096 s]. Out hi/lo planes.
// ---------------------------------------------------------------------------
__global__ __launch_bounds__(512) void attn_mfma(
    const unsigned short* __restrict__ qh, const unsigned short* __restrict__ kh,
    const unsigned short* __restrict__ vt, unsigned short* __restrict__ oh,
    unsigned short* __restrict__ ol) {
  __shared__ __align__(16) char smem[32768];  // 2 x (8KB K + 8KB Vt)
  const int t = threadIdx.x;
  const int lane = t & 63;
  const int wave = t >> 6;  // 0..7
  const int l15 = lane & 15;
  const int g = lane >> 4;
  // XCD swizzle (grid fixed at dim3(16, 8, 2); total = 256)
  const int orig = blockIdx.x + ((blockIdx.y + (blockIdx.z << 3)) << 4);
  const int work = ((orig & 7) << 5) + (orig >> 3);
  const int hd = (work >> 4) & 7;
  const int bz = work >> 7;
  const int q0 = (work & 15) * 256;
  const long sbase = (long)bz * SEQ * 512;
  const long tbase = (long)bz * 512 * SEQ;

  // pre-swizzled gll sources (8 rows per gll, 16B per lane; wave stages 8 rows)
  const int grow = lane >> 3;
  const int ch = (((lane & 7) << 4) ^ (grow << 4));
  const char* kG = (const char*)kh + (sbase << 1) + hd * 128 +
                   (long)(wave * 8 + grow) * 1024 + ch;  // + j0*1024
  const char* vG = (const char*)vt +
                   ((tbase + (long)(hd * 64 + wave * 8 + grow) * 4096) << 1) + ch;  // + j0*2

  const int swzl = (l15 & 7) << 4;
  const int kfb = l15 * 128 + g * 16;
  const int vfb = l15 * 128 + g * 8;

  // Q fragments for both q-tiles (scale+log2e already folded into Wq)
  bf16x8 qf[2][2];
#pragma unroll
  for (int u = 0; u < 2; ++u) {
    const unsigned short* qrow =
        qh + sbase + (long)(q0 + wave * 32 + u * 16 + l15) * 512 + hd * 64 + g * 8;
    qf[u][0] = *(const bf16x8*)(qrow);
    qf[u][1] = *(const bf16x8*)(qrow + 32);
  }

  // ones-row A-fragment: row 0 of the sum-tile is 1.0, rows 1..15 are 0.
  bf16x8 vones;
#pragma unroll
  for (int e = 0; e < 8; ++e) vones[e] = (l15 == 0) ? (short)0x3f80 : (short)0;

  f32x4 acc[2][4];
  f32x4 acc5[2];
#pragma unroll
  for (int u = 0; u < 2; ++u) {
    acc5[u] = (f32x4){0.f, 0.f, 0.f, 0.f};
#pragma unroll
    for (int dt = 0; dt < 4; ++dt) acc[u][dt] = (f32x4){0.f, 0.f, 0.f, 0.f};
  }

  // prologue: stage tile 0 -> buf0 (each wave: 1 K-gll + 1 V-gll)
  gll16(kG, smem + wave * 1024);
  gll16(vG, smem + 8192 + wave * 1024);

  int buf = 0;
  for (int j0 = 0; j0 < SEQ; j0 += 64) {
    char* Kl = smem + buf * 16384;
    char* Vl = Kl + 8192;
    __syncthreads();  // drains gll; tile j0 staged, prior reads done
    if (j0 + 64 < SEQ) {
      char* Kn = smem + (buf ^ 1) * 16384;
      gll16(kG + (long)(j0 + 64) * 1024, Kn + wave * 1024);
      gll16(vG + (long)(j0 + 64) * 2, Kn + 8192 + wave * 1024);
    }

    // S^T = K @ Q^T for both q-tiles (K-frags read once)
    f32x4 st[2][4];
    __builtin_amdgcn_s_setprio(1);
#pragma unroll
    for (int kt = 0; kt < 4; ++kt) {
      const bf16x8 ka0 = *(const bf16x8*)(Kl + ((kt * 2048 + kfb) ^ swzl));
      const bf16x8 ka1 = *(const bf16x8*)(Kl + ((kt * 2048 + kfb + 64) ^ swzl));
      f32x4 s0 = {0.f, 0.f, 0.f, 0.f};
      f32x4 s1 = {0.f, 0.f, 0.f, 0.f};
      s0 = __builtin_amdgcn_mfma_f32_16x16x32_bf16(ka0, qf[0][0], s0, 0, 0, 0);
      s0 = __builtin_amdgcn_mfma_f32_16x16x32_bf16(ka1, qf[0][1], s0, 0, 0, 0);
      s1 = __builtin_amdgcn_mfma_f32_16x16x32_bf16(ka0, qf[1][0], s1, 0, 0, 0);
      s1 = __builtin_amdgcn_mfma_f32_16x16x32_bf16(ka1, qf[1][1], s1, 0, 0, 0);
      st[0][kt] = s0;
      st[1][kt] = s1;
    }
    __builtin_amdgcn_s_setprio(0);

    // p = exp2(s) directly (scores tiny; shift-free softmax), pack to bf16
    union Pb { bf16x8 v8; unsigned u4[4]; } pb[2][2];
#pragma unroll
    for (int u = 0; u < 2; ++u) {
#pragma unroll
      for (int kt = 0; kt < 4; ++kt)
#pragma unroll
        for (int r = 0; r < 4; ++r)
          st[u][kt][r] = __builtin_amdgcn_exp2f(st[u][kt][r]);
#pragma unroll
      for (int kc = 0; kc < 2; ++kc)
#pragma unroll
        for (int h = 0; h < 2; ++h) {
          pb[u][kc].u4[h * 2 + 0] = pk2bf(st[u][2 * kc + h][0], st[u][2 * kc + h][1]);
          pb[u][kc].u4[h * 2 + 1] = pk2bf(st[u][2 * kc + h][2], st[u][2 * kc + h][3]);
        }
    }

    // O^T += V^T @ P^T (V-frags shared across q-tiles) + row-sum via vones
    __builtin_amdgcn_s_setprio(1);
#pragma unroll
    for (int dt = 0; dt < 4; ++dt) {
      union { bf16x8 v8; int2 h2[2]; } va0, va1;
      va0.h2[0] = *(const int2*)(Vl + ((dt * 2048 + vfb) ^ swzl));
      va0.h2[1] = *(const int2*)(Vl + ((dt * 2048 + vfb + 32) ^ swzl));
      va1.h2[0] = *(const int2*)(Vl + ((dt * 2048 + vfb + 64) ^ swzl));
      va1.h2[1] = *(const int2*)(Vl + ((dt * 2048 + vfb + 96) ^ swzl));
      acc[0][dt] = __builtin_amdgcn_mfma_f32_16x16x32_bf16(va0.v8, pb[0][0].v8, acc[0][dt], 0, 0, 0);
      acc[0][dt] = __builtin_amdgcn_mfma_f32_16x16x32_bf16(va1.v8, pb[0][1].v8, acc[0][dt], 0, 0, 0);
      acc[1][dt] = __builtin_amdgcn_mfma_f32_16x16x32_bf16(va0.v8, pb[1][0].v8, acc[1][dt], 0, 0, 0);
      acc[1][dt] = __builtin_amdgcn_mfma_f32_16x16x32_bf16(va1.v8, pb[1][1].v8, acc[1][dt], 0, 0, 0);
    }
#pragma unroll
    for (int u = 0; u < 2; ++u) {
      acc5[u] = __builtin_amdgcn_mfma_f32_16x16x32_bf16(vones, pb[u][0].v8, acc5[u], 0, 0, 0);
      acc5[u] = __builtin_amdgcn_mfma_f32_16x16x32_bf16(vones, pb[u][1].v8, acc5[u], 0, 0, 0);
    }
    __builtin_amdgcn_s_setprio(0);
    buf ^= 1;
  }

  // epilogue: l = row-sum (D row 0 lives in lanes g==0, reg 0, col=l15)
#pragma unroll
  for (int u = 0; u < 2; ++u) {
    const float lt = __shfl(acc5[u][0], l15);
    const float inv = 1.0f / lt;
    const long orow = sbase + (long)(q0 + wave * 32 + u * 16 + l15) * 512 + hd * 64;
#pragma unroll
    for (int dt = 0; dt < 4; ++dt) {
      short h[4], l[4];
#pragma unroll
      for (int r = 0; r < 4; ++r) {
        const float v = acc[u][dt][r] * inv;
        h[r] = f2bf(v);
        l[r] = f2bf(v - bf2f(h[r]));
      }
      *(short4*)(oh + orow + dt * 16 + g * 4) = make_short4(h[0], h[1], h[2], h[3]);
      *(short4*)(ol + orow + dt * 16 + g * 4) = make_short4(l[0], l[1], l[2], l[3]);
    }
  }
}

// ---------------------------------------------------------------------------
extern "C" void kernel_launch(void* const* d_in, const int* in_sizes, int n_in,
                              void* d_out, int out_size, void* d_ws,
                              size_t ws_size, hipStream_t stream) {
  const float* x   = (const float*)d_in[0];
  const float* ctx = (const float*)d_in[1];
  const float* Wi  = (const float*)d_in[2];
  const float* bi  = (const float*)d_in[3];
  const float* Wc  = (const float*)d_in[4];
  const float* bc  = (const float*)d_in[5];
  const float* Wq  = (const float*)d_in[6];
  const float* Wk  = (const float*)d_in[7];
  const float* Wv  = (const float*)d_in[8];
  const float* Wo1 = (const float*)d_in[9];
  const float* bo1 = (const float*)d_in[10];
  const float* Wo2 = (const float*)d_in[11];
  const float* bo2 = (const float*)d_in[12];
  float* out = (float*)d_out;

  const size_t WP = 262144;  // elements per weight plane
  char* p = (char*)d_ws;
  unsigned short* wth = (unsigned short*)p; p += (size_t)7 * WP * 2;
  unsigned short* wtl = (unsigned short*)p; p += (size_t)7 * WP * 2;
  unsigned short* cwh = (unsigned short*)p; p += (size_t)3 * WP * 2;  // collapsed hi
  unsigned short* cwl = (unsigned short*)p; p += (size_t)3 * WP * 2;  // collapsed lo
  float* bqkv = (float*)p; p += 3 * 512 * 4;                          // bq, bk, bv
  const size_t PLE = (size_t)NB * SEQ * 512;  // elements per act plane
  unsigned short* P1 = (unsigned short*)p; p += PLE * 2;
  unsigned short* P2 = (unsigned short*)p; p += PLE * 2;
  unsigned short* P3 = (unsigned short*)p; p += PLE * 2;
  unsigned short* P4 = (unsigned short*)p; p += PLE * 2;
  unsigned short* P5 = (unsigned short*)p; p += PLE * 2;
  unsigned short* P6 = (unsigned short*)p; p += PLE * 2;
  // d_out (16.78 MB) doubles as the V^T bf16 plane until the final GEMM
  unsigned short* P7 = (unsigned short*)d_out;

  const dim3 gb(256);
  const dim3 pg(16, 16, 8), pbk(32, 8);
  const dim3 xg(128, 16, 2 * NB);
  GemmJob jn = {};

  // weights + collapsed biases in one launch; x/ctx transpose-split
  prep_w<<<pg, pbk, 0, stream>>>(Wi, Wc, Wq, Wk, Wv, Wo1, Wo2, bi, bc,
                                 wth, wtl, bqkv);
  prep_x2<<<xg, pbk, 0, stream>>>(x, ctx, P1, P2, P3, P4);
  // weight collapse: Wiq^T = Wqt@Wi_nt ; Wck^T = Wkt@Wc_nt ; Wcv^T = Wvt@Wc_nt
  {
    GemmJob ja = {wth + 2 * WP, wtl + 2 * WP, wth + 0 * WP, wtl + 0 * WP,
                  nullptr, cwh + 0 * WP, cwl + 0 * WP, 0};
    GemmJob jb = {wth + 3 * WP, wtl + 3 * WP, wth + 1 * WP, wtl + 1 * WP,
                  nullptr, cwh + 1 * WP, cwl + 1 * WP, 0};
    GemmJob jc = {wth + 4 * WP, wtl + 4 * WP, wth + 1 * WP, wtl + 1 * WP,
                  nullptr, cwh + 2 * WP, cwl + 2 * WP, 0};
    gemmN<OUT_DUAL, false, false, 3, 4, 1><<<dim3(8, 4, 3), gb, 0, stream>>>(ja, jb, jc);
  }
  // fused QKV straight from x/ctx: Q -> P5 ; K -> P6 ; V^T -> P7 (d_out)
  {
    GemmJob ja = {P1, P2, cwh + 0 * WP, cwl + 0 * WP, bqkv + 0, P5, nullptr, 0};
    GemmJob jb = {P3, P4, cwh + 1 * WP, cwl + 1 * WP, bqkv + 512, P6, nullptr, 0};
    GemmJob jc = {P3, P4, cwh + 2 * WP, cwl + 2 * WP, bqkv + 1024, P7, nullptr, 1};
    gemmN<OUT_HI, false, true, 3, 32, 2><<<dim3(8, 32, 6), gb, 0, stream>>>(ja, jb, jc);
  }
  // attention(Q=P5, K=P6, Vt=P7) -> P1 (hi), P2 (lo)
  attn_mfma<<<dim3(SEQ / 256, NHEADS, NB), dim3(512), 0, stream>>>(P5, P6, P7, P1, P2);
  // t1 = gelu(attn @ Wo1 + bo1) -> P3 (hi), P4 (lo)
  {
    GemmJob j = {P1, P2, wth + 5 * WP, wtl + 5 * WP, bo1, P3, P4, 0};
    gemmN<OUT_DUAL, true, true, 1, 32, 2><<<dim3(8, 32, 2), gb, 0, stream>>>(j, jn, jn);
  }
  // out[b][c][s] = (t1 @ Wo2 + bo2)^T (fp32, fused transpose store)
  {
    GemmJob j = {P3, P4, wth + 6 * WP, wtl + 6 * WP, bo2, out, nullptr, 1};
    gemmN<OUT_F32, false, true, 1, 32, 2><<<dim3(8, 32, 2), gb, 0, stream>>>(j, jn, jn);
  }
}

// Round 17
// 213.965 us; speedup vs baseline: 1.1279x; 1.1279x over previous
//
#include <hip/hip_runtime.h>

#define SEQ 4096
#define CDIM 512
#define HID 512
#define NB 2
#define NHEADS 8

typedef float f32x4 __attribute__((ext_vector_type(4)));
typedef short bf16x8 __attribute__((ext_vector_type(8)));

static __device__ __forceinline__ short f2bf(float f) {
  unsigned u = __float_as_uint(f);
  u = (u + 0x7fffu + ((u >> 16) & 1u)) >> 16;
  return (short)u;
}
static __device__ __forceinline__ float bf2f(short h) {
  return __uint_as_float(((unsigned)(unsigned short)h) << 16);
}
static __device__ __forceinline__ unsigned pk2bf(float a, float b) {
  unsigned r;
  asm("v_cvt_pk_bf16_f32 %0, %1, %2" : "=v"(r) : "v"(a), "v"(b));
  return r;
}
// async global->LDS, 16B per lane; LDS dest = wave-uniform base + lane*16
typedef const __attribute__((address_space(1))) char gas_char;
typedef __attribute__((address_space(3))) char las_char;
static __device__ __forceinline__ void gll16(const char* g, char* l) {
  __builtin_amdgcn_global_load_lds((gas_char*)g, (las_char*)l, 16, 0, 0);
}

// ---------------------------------------------------------------------------
// prep_w: fp32 weights -> bf16 hi/lo splits.
// z=0: Wi NON-transposed [k][n] (collapse B-operand)
// z=1: Wc NON-transposed [k][n]
// z=2..6: Wq (scaled by 0.125*log2e), Wk, Wv, Wo1, Wo2 transposed [n][k]
// ---------------------------------------------------------------------------
__global__ __launch_bounds__(256) void prep_w(
    const float* Wi, const float* Wc, const float* Wq, const float* Wk,
    const float* Wv, const float* Wo1, const float* Wo2,
    unsigned short* wth, unsigned short* wtl) {
  __shared__ float tile[32][33];
  const int z = blockIdx.z;
  const float* src;
  float scale = 1.0f;
  switch (z) {
    case 0: src = Wi; break;
    case 1: src = Wc; break;
    case 2: src = Wq; scale = 0.18033688011112042f; break;  // 0.125*log2(e)
    case 3: src = Wk; break;
    case 4: src = Wv; break;
    case 5: src = Wo1; break;
    default: src = Wo2; break;
  }
  const int n0 = blockIdx.x * 32, k0 = blockIdx.y * 32;
  const int tx = threadIdx.x, ty = threadIdx.y;
  for (int i = ty; i < 32; i += 8)
    tile[i][tx] = src[(k0 + i) * 512 + n0 + tx];
  __syncthreads();
  unsigned short* oh = wth + z * 262144;
  unsigned short* ol = wtl + z * 262144;
  if (z < 2) {
    for (int i = ty; i < 32; i += 8) {
      const float v = tile[i][tx];  // = W[k0+i][n0+tx]
      const short h = f2bf(v);
      oh[(k0 + i) * 512 + n0 + tx] = (unsigned short)h;
      ol[(k0 + i) * 512 + n0 + tx] = (unsigned short)f2bf(v - bf2f(h));
    }
  } else {
    for (int i = ty; i < 32; i += 8) {
      const float v = tile[tx][i] * scale;  // = W[k0+tx][n0+i]*scale
      const short h = f2bf(v);
      oh[(n0 + i) * 512 + k0 + tx] = (unsigned short)h;
      ol[(n0 + i) * 512 + k0 + tx] = (unsigned short)f2bf(v - bf2f(h));
    }
  }
}

// ---------------------------------------------------------------------------
// prep_bias: collapsed biases bq = (bi@Wq)*s, bk = bc@Wk, bv = bc@Wv.
// ---------------------------------------------------------------------------
__global__ __launch_bounds__(512) void prep_bias(
    const float* __restrict__ bi, const float* __restrict__ Wq,
    const float* __restrict__ bc, const float* __restrict__ Wk,
    const float* __restrict__ Wv, float* __restrict__ bout) {
  const int z = blockIdx.x;
  const int n = threadIdx.x;
  const float* b = (z == 0) ? bi : bc;
  const float* W = (z == 0) ? Wq : (z == 1) ? Wk : Wv;
  const float s = (z == 0) ? 0.18033688011112042f : 1.0f;
  float acc = 0.0f;
  for (int k = 0; k < 512; ++k) acc += b[k] * W[k * 512 + n];
  bout[z * 512 + n] = acc * s;
}

// ---------------------------------------------------------------------------
// prep_x2: {x, ctx} [b][c][s] fp32 -> hi/lo planes [b][s][c] bf16 (one launch)
// ---------------------------------------------------------------------------
__global__ __launch_bounds__(256) void prep_x2(
    const float* __restrict__ x, const float* __restrict__ ctx,
    unsigned short* __restrict__ oh0, unsigned short* __restrict__ ol0,
    unsigned short* __restrict__ oh1, unsigned short* __restrict__ ol1) {
  __shared__ float tile[32][33];
  const int b = blockIdx.z & 1;
  const int ten = blockIdx.z >> 1;
  const float* in = ten ? ctx : x;
  unsigned short* oh = ten ? oh1 : oh0;
  unsigned short* ol = ten ? ol1 : ol0;
  const int s0 = blockIdx.x * 32, c0 = blockIdx.y * 32;
  const int tx = threadIdx.x, ty = threadIdx.y;
  const float* ib = in + (long)b * CDIM * SEQ;
  for (int i = ty; i < 32; i += 8)
    tile[i][tx] = ib[(long)(c0 + i) * SEQ + s0 + tx];
  __syncthreads();
  const long ob = (long)b * SEQ * CDIM;
  for (int i = ty; i < 32; i += 8) {
    const float v = tile[tx][i];
    const short h = f2bf(v);
    oh[ob + (long)(s0 + i) * CDIM + c0 + tx] = (unsigned short)h;
    ol[ob + (long)(s0 + i) * CDIM + c0 + tx] = (unsigned short)f2bf(v - bf2f(h));
  }
}

// ---------------------------------------------------------------------------
// Split-bf16 MFMA GEMM, tile 128(M)x64(N), 4 waves, BK=32, double-buffered
// via global_load_lds (pre-swizzled per-lane source, linear LDS dest).
// Loop: {sync(drains gll); issue gll next->buf^1; MFMA from buf}.
// Y = Ah Wh + Ah Wl + Al Wh (fp32 acc). LDS rows 128B [hi|lo], XOR-swizzled.
// Template GY = #m-tiles (M = GY*128), NBATCH = batches. XCD-aware swizzle.
// ---------------------------------------------------------------------------
#define OUT_DUAL 0
#define OUT_HI 1
#define OUT_F32 2

struct GemmJob {
  const unsigned short *Ah, *Al, *Wh, *Wl;
  const float* bias;
  void *outA, *outB;
  int tstore;
};

template <int OMODE, bool DO_GELU, bool HASB, int NJOBS, int GY, int NBATCH>
__global__ __launch_bounds__(256) void gemmN(GemmJob J0, GemmJob J1, GemmJob J2) {
  __shared__ __align__(16) char lds[49152];  // 2 x (16KB A + 8KB W)
  // XCD swizzle over grid dim3(8, GY, NBATCH*NJOBS)
  const int orig = blockIdx.x + ((blockIdx.y + blockIdx.z * GY) << 3);
  const int total = 8 * GY * NBATCH * NJOBS;
  const int work = (orig & 7) * (total >> 3) + (orig >> 3);
  const int bx = work & 7;
  const int rest = work >> 3;
  const int by = rest % GY;
  const int z = rest / GY;
  const int jz = z / NBATCH;
  const int bz = z % NBATCH;
  const GemmJob J = (NJOBS >= 3 && jz == 2) ? J2 : ((NJOBS >= 2 && jz == 1) ? J1 : J0);
  const int TS = J.tstore;
  const int t = threadIdx.x;
  const int lane = t & 63, wave = t >> 6;
  const int l15 = lane & 15, g = lane >> 4;
  const int m0 = by * 128, n0 = bx * 64;
  const long abase = (long)bz * SEQ * 512;

  const int grow = lane >> 3;                       // row within gll
  const int ch = (((lane & 7) << 4) ^ (grow << 4)); // swizzled byte in 128B row
  const int chp = ch & 63;                          // byte within 64B plane slice
  const char* pa = (const char*)((ch < 64) ? J.Ah : J.Al);
  const char* pw = (const char*)((ch < 64) ? J.Wh : J.Wl);
  const char* aG[4];
#pragma unroll
  for (int i = 0; i < 4; ++i)
    aG[i] = pa + ((abase + (long)(m0 + wave * 32 + i * 8 + grow) * 512) << 1) + chp;
  const char* wG[2];
#pragma unroll
  for (int i = 0; i < 2; ++i)
    wG[i] = pw + (((long)(n0 + wave * 16 + i * 8 + grow) * 512) << 1) + chp;

  f32x4 acc[4][2];
#pragma unroll
  for (int p = 0; p < 4; ++p)
#pragma unroll
    for (int q = 0; q < 2; ++q) acc[p][q] = (f32x4){0.f, 0.f, 0.f, 0.f};

  {
    char* LA = lds;
    char* LW = lds + 16384;
#pragma unroll
    for (int i = 0; i < 4; ++i) gll16(aG[i], LA + wave * 4096 + i * 1024);
#pragma unroll
    for (int i = 0; i < 2; ++i) gll16(wG[i], LW + wave * 2048 + i * 1024);
  }

  int buf = 0;
  for (int k0 = 0; k0 < 512; k0 += 32) {
    char* LA = lds + buf * 24576;
    char* LW = LA + 16384;
    __syncthreads();  // drains gll (vmcnt 0) + protects write-after-read
    if (k0 + 32 < 512) {
      char* NA = lds + (buf ^ 1) * 24576;
      char* NW = NA + 16384;
      const int koff = (k0 + 32) * 2;
#pragma unroll
      for (int i = 0; i < 4; ++i) gll16(aG[i] + koff, NA + wave * 4096 + i * 1024);
#pragma unroll
      for (int i = 0; i < 2; ++i) gll16(wG[i] + koff, NW + wave * 2048 + i * 1024);
    }

    if (!TS) {
      bf16x8 fbh[2], fbl[2];
#pragma unroll
      for (int q = 0; q < 2; ++q) {
        const int r = wave * 32 + q * 16 + l15;
        const char* rp = LA + r * 128;
        const int sw = (r & 7) << 4;
        fbh[q] = *(const bf16x8*)(rp + ((g << 4) ^ sw));
        fbl[q] = *(const bf16x8*)(rp + (((4 + g) << 4) ^ sw));
      }
#pragma unroll
      for (int p = 0; p < 4; ++p) {
        const int r = p * 16 + l15;
        const char* rp = LW + r * 128;
        const int sw = (r & 7) << 4;
        const bf16x8 fah = *(const bf16x8*)(rp + ((g << 4) ^ sw));
        const bf16x8 fal = *(const bf16x8*)(rp + (((4 + g) << 4) ^ sw));
#pragma unroll
        for (int q = 0; q < 2; ++q) {
          acc[p][q] = __builtin_amdgcn_mfma_f32_16x16x32_bf16(fah, fbh[q], acc[p][q], 0, 0, 0);
          acc[p][q] = __builtin_amdgcn_mfma_f32_16x16x32_bf16(fah, fbl[q], acc[p][q], 0, 0, 0);
          acc[p][q] = __builtin_amdgcn_mfma_f32_16x16x32_bf16(fal, fbh[q], acc[p][q], 0, 0, 0);
        }
      }
    } else {
      const int mB = (wave >> 1) * 64, nB = (wave & 1) * 32;
      bf16x8 fbh[2], fbl[2];
#pragma unroll
      for (int q = 0; q < 2; ++q) {
        const int r = nB + q * 16 + l15;
        const char* rp = LW + r * 128;
        const int sw = (r & 7) << 4;
        fbh[q] = *(const bf16x8*)(rp + ((g << 4) ^ sw));
        fbl[q] = *(const bf16x8*)(rp + (((4 + g) << 4) ^ sw));
      }
#pragma unroll
      for (int p = 0; p < 4; ++p) {
        const int r = mB + p * 16 + l15;
        const char* rp = LA + r * 128;
        const int sw = (r & 7) << 4;
        const bf16x8 fah = *(const bf16x8*)(rp + ((g << 4) ^ sw));
        const bf16x8 fal = *(const bf16x8*)(rp + (((4 + g) << 4) ^ sw));
#pragma unroll
        for (int q = 0; q < 2; ++q) {
          acc[p][q] = __builtin_amdgcn_mfma_f32_16x16x32_bf16(fah, fbh[q], acc[p][q], 0, 0, 0);
          acc[p][q] = __builtin_amdgcn_mfma_f32_16x16x32_bf16(fah, fbl[q], acc[p][q], 0, 0, 0);
          acc[p][q] = __builtin_amdgcn_mfma_f32_16x16x32_bf16(fal, fbh[q], acc[p][q], 0, 0, 0);
        }
      }
    }
    buf ^= 1;
  }

  const long obase = (long)bz * 512 * SEQ;
#pragma unroll
  for (int p = 0; p < 4; ++p)
#pragma unroll
    for (int q = 0; q < 2; ++q) {
      f32x4 v = acc[p][q];
      if (TS) {
        const int m = m0 + (wave >> 1) * 64 + p * 16 + 4 * g;  // vector spans m
        const int n = n0 + (wave & 1) * 32 + q * 16 + l15;
        if (HASB) {
          const float b = J.bias[n];
          v[0] += b; v[1] += b; v[2] += b; v[3] += b;
        }
        if (OMODE == OUT_F32) {
          float4 f;
          f.x = v[0]; f.y = v[1]; f.z = v[2]; f.w = v[3];
          *(float4*)((float*)J.outA + obase + (long)n * SEQ + m) = f;
        } else {
          const short4 h4 = make_short4(f2bf(v[0]), f2bf(v[1]), f2bf(v[2]), f2bf(v[3]));
          *(short4*)((unsigned short*)J.outA + obase + (long)n * SEQ + m) = h4;
        }
      } else {
        const int n = n0 + p * 16 + 4 * g;  // vector spans n
        const int m = m0 + wave * 32 + q * 16 + l15;
        if (HASB) v += *(const f32x4*)(J.bias + n);
        if (DO_GELU) {
#pragma unroll
          for (int r = 0; r < 4; ++r)
            v[r] = 0.5f * v[r] * (1.0f + erff(v[r] * 0.7071067811865476f));
        }
        unsigned short* oA = (unsigned short*)J.outA + obase + (long)m * 512 + n;
        if (OMODE == OUT_DUAL) {
          short h[4], l[4];
#pragma unroll
          for (int r = 0; r < 4; ++r) {
            h[r] = f2bf(v[r]);
            l[r] = f2bf(v[r] - bf2f(h[r]));
          }
          *(short4*)oA = make_short4(h[0], h[1], h[2], h[3]);
          *(short4*)((unsigned short*)J.outB + obase + (long)m * 512 + n) =
              make_short4(l[0], l[1], l[2], l[3]);
        } else {
          *(short4*)oA = make_short4(f2bf(v[0]), f2bf(v[1]), f2bf(v[2]), f2bf(v[3]));
        }
      }
    }
}

// ---------------------------------------------------------------------------
// Flash attention, bf16 MFMA. 8 waves x 512 thr; QBLK=256 (2 x 16 q-rows per
// wave), KVBLK=64, gll16 staging, zero-shuffle exp2 softmax, MFMA row-sum,
// XCD swizzle. Q,K planes [b][s][512]; Vt [b][512 d][4096 s]. Out hi/lo.
// ---------------------------------------------------------------------------
__global__ __launch_bounds__(512) void attn_mfma(
    const unsigned short* __restrict__ qh, const unsigned short* __restrict__ kh,
    const unsigned short* __restrict__ vt, unsigned short* __restrict__ oh,
    unsigned short* __restrict__ ol) {
  __shared__ __align__(16) char smem[32768];  // 2 x (8KB K + 8KB Vt)
  const int t = threadIdx.x;
  const int lane = t & 63;
  const int wave = t >> 6;  // 0..7
  const int l15 = lane & 15;
  const int g = lane >> 4;
  // XCD swizzle (grid fixed at dim3(16, 8, 2); total = 256)
  const int orig = blockIdx.x + ((blockIdx.y + (blockIdx.z << 3)) << 4);
  const int work = ((orig & 7) << 5) + (orig >> 3);
  const int hd = (work >> 4) & 7;
  const int bz = work >> 7;
  const int q0 = (work & 15) * 256;
  const long sbase = (long)bz * SEQ * 512;
  const long tbase = (long)bz * 512 * SEQ;

  // pre-swizzled gll sources (8 rows per gll, 16B per lane; wave stages 8 rows)
  const int grow = lane >> 3;
  const int ch = (((lane & 7) << 4) ^ (grow << 4));
  const char* kG = (const char*)kh + (sbase << 1) + hd * 128 +
                   (long)(wave * 8 + grow) * 1024 + ch;  // + j0*1024
  const char* vG = (const char*)vt +
                   ((tbase + (long)(hd * 64 + wave * 8 + grow) * 4096) << 1) + ch;  // + j0*2

  const int swzl = (l15 & 7) << 4;
  const int kfb = l15 * 128 + g * 16;
  const int vfb = l15 * 128 + g * 8;

  // Q fragments for both q-tiles (scale+log2e already folded into Wq)
  bf16x8 qf[2][2];
#pragma unroll
  for (int u = 0; u < 2; ++u) {
    const unsigned short* qrow =
        qh + sbase + (long)(q0 + wave * 32 + u * 16 + l15) * 512 + hd * 64 + g * 8;
    qf[u][0] = *(const bf16x8*)(qrow);
    qf[u][1] = *(const bf16x8*)(qrow + 32);
  }

  // ones-row A-fragment: row 0 of the sum-tile is 1.0, rows 1..15 are 0.
  bf16x8 vones;
#pragma unroll
  for (int e = 0; e < 8; ++e) vones[e] = (l15 == 0) ? (short)0x3f80 : (short)0;

  f32x4 acc[2][4];
  f32x4 acc5[2];
#pragma unroll
  for (int u = 0; u < 2; ++u) {
    acc5[u] = (f32x4){0.f, 0.f, 0.f, 0.f};
#pragma unroll
    for (int dt = 0; dt < 4; ++dt) acc[u][dt] = (f32x4){0.f, 0.f, 0.f, 0.f};
  }

  // prologue: stage tile 0 -> buf0 (each wave: 1 K-gll + 1 V-gll)
  gll16(kG, smem + wave * 1024);
  gll16(vG, smem + 8192 + wave * 1024);

  int buf = 0;
  for (int j0 = 0; j0 < SEQ; j0 += 64) {
    char* Kl = smem + buf * 16384;
    char* Vl = Kl + 8192;
    __syncthreads();  // drains gll; tile j0 staged, prior reads done
    if (j0 + 64 < SEQ) {
      char* Kn = smem + (buf ^ 1) * 16384;
      gll16(kG + (long)(j0 + 64) * 1024, Kn + wave * 1024);
      gll16(vG + (long)(j0 + 64) * 2, Kn + 8192 + wave * 1024);
    }

    // S^T = K @ Q^T for both q-tiles (K-frags read once)
    f32x4 st[2][4];
    __builtin_amdgcn_s_setprio(1);
#pragma unroll
    for (int kt = 0; kt < 4; ++kt) {
      const bf16x8 ka0 = *(const bf16x8*)(Kl + ((kt * 2048 + kfb) ^ swzl));
      const bf16x8 ka1 = *(const bf16x8*)(Kl + ((kt * 2048 + kfb + 64) ^ swzl));
      f32x4 s0 = {0.f, 0.f, 0.f, 0.f};
      f32x4 s1 = {0.f, 0.f, 0.f, 0.f};
      s0 = __builtin_amdgcn_mfma_f32_16x16x32_bf16(ka0, qf[0][0], s0, 0, 0, 0);
      s0 = __builtin_amdgcn_mfma_f32_16x16x32_bf16(ka1, qf[0][1], s0, 0, 0, 0);
      s1 = __builtin_amdgcn_mfma_f32_16x16x32_bf16(ka0, qf[1][0], s1, 0, 0, 0);
      s1 = __builtin_amdgcn_mfma_f32_16x16x32_bf16(ka1, qf[1][1], s1, 0, 0, 0);
      st[0][kt] = s0;
      st[1][kt] = s1;
    }
    __builtin_amdgcn_s_setprio(0);

    // p = exp2(s) directly (scores tiny; shift-free softmax), pack to bf16
    union Pb { bf16x8 v8; unsigned u4[4]; } pb[2][2];
#pragma unroll
    for (int u = 0; u < 2; ++u) {
#pragma unroll
      for (int kt = 0; kt < 4; ++kt)
#pragma unroll
        for (int r = 0; r < 4; ++r)
          st[u][kt][r] = __builtin_amdgcn_exp2f(st[u][kt][r]);
#pragma unroll
      for (int kc = 0; kc < 2; ++kc)
#pragma unroll
        for (int h = 0; h < 2; ++h) {
          pb[u][kc].u4[h * 2 + 0] = pk2bf(st[u][2 * kc + h][0], st[u][2 * kc + h][1]);
          pb[u][kc].u4[h * 2 + 1] = pk2bf(st[u][2 * kc + h][2], st[u][2 * kc + h][3]);
        }
    }

    // O^T += V^T @ P^T (V-frags shared across q-tiles) + row-sum via vones
    __builtin_amdgcn_s_setprio(1);
#pragma unroll
    for (int dt = 0; dt < 4; ++dt) {
      union { bf16x8 v8; int2 h2[2]; } va0, va1;
      va0.h2[0] = *(const int2*)(Vl + ((dt * 2048 + vfb) ^ swzl));
      va0.h2[1] = *(const int2*)(Vl + ((dt * 2048 + vfb + 32) ^ swzl));
      va1.h2[0] = *(const int2*)(Vl + ((dt * 2048 + vfb + 64) ^ swzl));
      va1.h2[1] = *(const int2*)(Vl + ((dt * 2048 + vfb + 96) ^ swzl));
      acc[0][dt] = __builtin_amdgcn_mfma_f32_16x16x32_bf16(va0.v8, pb[0][0].v8, acc[0][dt], 0, 0, 0);
      acc[0][dt] = __builtin_amdgcn_mfma_f32_16x16x32_bf16(va1.v8, pb[0][1].v8, acc[0][dt], 0, 0, 0);
      acc[1][dt] = __builtin_amdgcn_mfma_f32_16x16x32_bf16(va0.v8, pb[1][0].v8, acc[1][dt], 0, 0, 0);
      acc[1][dt] = __builtin_amdgcn_mfma_f32_16x16x32_bf16(va1.v8, pb[1][1].v8, acc[1][dt], 0, 0, 0);
    }
#pragma unroll
    for (int u = 0; u < 2; ++u) {
      acc5[u] = __builtin_amdgcn_mfma_f32_16x16x32_bf16(vones, pb[u][0].v8, acc5[u], 0, 0, 0);
      acc5[u] = __builtin_amdgcn_mfma_f32_16x16x32_bf16(vones, pb[u][1].v8, acc5[u], 0, 0, 0);
    }
    __builtin_amdgcn_s_setprio(0);
    buf ^= 1;
  }

  // epilogue: l = row-sum (D row 0 lives in lanes g==0, reg 0, col=l15)
#pragma unroll
  for (int u = 0; u < 2; ++u) {
    const float lt = __shfl(acc5[u][0], l15);
    const float inv = 1.0f / lt;
    const long orow = sbase + (long)(q0 + wave * 32 + u * 16 + l15) * 512 + hd * 64;
#pragma unroll
    for (int dt = 0; dt < 4; ++dt) {
      short h[4], l[4];
#pragma unroll
      for (int r = 0; r < 4; ++r) {
        const float v = acc[u][dt][r] * inv;
        h[r] = f2bf(v);
        l[r] = f2bf(v - bf2f(h[r]));
      }
      *(short4*)(oh + orow + dt * 16 + g * 4) = make_short4(h[0], h[1], h[2], h[3]);
      *(short4*)(ol + orow + dt * 16 + g * 4) = make_short4(l[0], l[1], l[2], l[3]);
    }
  }
}

// ---------------------------------------------------------------------------
extern "C" void kernel_launch(void* const* d_in, const int* in_sizes, int n_in,
                              void* d_out, int out_size, void* d_ws,
                              size_t ws_size, hipStream_t stream) {
  const float* x   = (const float*)d_in[0];
  const float* ctx = (const float*)d_in[1];
  const float* Wi  = (const float*)d_in[2];
  const float* bi  = (const float*)d_in[3];
  const float* Wc  = (const float*)d_in[4];
  const float* bc  = (const float*)d_in[5];
  const float* Wq  = (const float*)d_in[6];
  const float* Wk  = (const float*)d_in[7];
  const float* Wv  = (const float*)d_in[8];
  const float* Wo1 = (const float*)d_in[9];
  const float* bo1 = (const float*)d_in[10];
  const float* Wo2 = (const float*)d_in[11];
  const float* bo2 = (const float*)d_in[12];
  float* out = (float*)d_out;

  const size_t WP = 262144;  // elements per weight plane
  char* p = (char*)d_ws;
  unsigned short* wth = (unsigned short*)p; p += (size_t)7 * WP * 2;
  unsigned short* wtl = (unsigned short*)p; p += (size_t)7 * WP * 2;
  unsigned short* cwh = (unsigned short*)p; p += (size_t)3 * WP * 2;  // collapsed hi
  unsigned short* cwl = (unsigned short*)p; p += (size_t)3 * WP * 2;  // collapsed lo
  float* bqkv = (float*)p; p += 3 * 512 * 4;                          // bq, bk, bv
  const size_t PLE = (size_t)NB * SEQ * 512;  // elements per act plane
  unsigned short* P1 = (unsigned short*)p; p += PLE * 2;
  unsigned short* P2 = (unsigned short*)p; p += PLE * 2;
  unsigned short* P3 = (unsigned short*)p; p += PLE * 2;
  unsigned short* P4 = (unsigned short*)p; p += PLE * 2;
  unsigned short* P5 = (unsigned short*)p; p += PLE * 2;
  unsigned short* P6 = (unsigned short*)p; p += PLE * 2;
  // d_out (16.78 MB) doubles as the V^T bf16 plane until the final GEMM
  unsigned short* P7 = (unsigned short*)d_out;

  const dim3 gb(256);
  const dim3 pg(16, 16, 7), pbk(32, 8);
  const dim3 xg(128, 16, 2 * NB);
  GemmJob jn = {};

  prep_w<<<pg, pbk, 0, stream>>>(Wi, Wc, Wq, Wk, Wv, Wo1, Wo2, wth, wtl);
  prep_bias<<<dim3(3), dim3(512), 0, stream>>>(bi, Wq, bc, Wk, Wv, bqkv);
  // x -> P1,P2 ; ctx -> P3,P4
  prep_x2<<<xg, pbk, 0, stream>>>(x, ctx, P1, P2, P3, P4);
  // weight collapse: Wiq^T = Wqt@Wi_nt ; Wck^T = Wkt@Wc_nt ; Wcv^T = Wvt@Wc_nt
  {
    GemmJob ja = {wth + 2 * WP, wtl + 2 * WP, wth + 0 * WP, wtl + 0 * WP,
                  nullptr, cwh + 0 * WP, cwl + 0 * WP, 0};
    GemmJob jb = {wth + 3 * WP, wtl + 3 * WP, wth + 1 * WP, wtl + 1 * WP,
                  nullptr, cwh + 1 * WP, cwl + 1 * WP, 0};
    GemmJob jc = {wth + 4 * WP, wtl + 4 * WP, wth + 1 * WP, wtl + 1 * WP,
                  nullptr, cwh + 2 * WP, cwl + 2 * WP, 0};
    gemmN<OUT_DUAL, false, false, 3, 4, 1><<<dim3(8, 4, 3), gb, 0, stream>>>(ja, jb, jc);
  }
  // fused QKV straight from x/ctx: Q -> P5 ; K -> P6 ; V^T -> P7 (d_out)
  {
    GemmJob ja = {P1, P2, cwh + 0 * WP, cwl + 0 * WP, bqkv + 0, P5, nullptr, 0};
    GemmJob jb = {P3, P4, cwh + 1 * WP, cwl + 1 * WP, bqkv + 512, P6, nullptr, 0};
    GemmJob jc = {P3, P4, cwh + 2 * WP, cwl + 2 * WP, bqkv + 1024, P7, nullptr, 1};
    gemmN<OUT_HI, false, true, 3, 32, 2><<<dim3(8, 32, 6), gb, 0, stream>>>(ja, jb, jc);
  }
  // attention(Q=P5, K=P6, Vt=P7) -> P1 (hi), P2 (lo)
  attn_mfma<<<dim3(SEQ / 256, NHEADS, NB), dim3(512), 0, stream>>>(P5, P6, P7, P1, P2);
  // t1 = gelu(attn @ Wo1 + bo1) -> P3 (hi), P4 (lo)
  {
    GemmJob j = {P1, P2, wth + 5 * WP, wtl + 5 * WP, bo1, P3, P4, 0};
    gemmN<OUT_DUAL, true, true, 1, 32, 2><<<dim3(8, 32, 2), gb, 0, stream>>>(j, jn, jn);
  }
  // out[b][c][s] = (t1 @ Wo2 + bo2)^T (fp32, fused transpose store)
  {
    GemmJob j = {P3, P4, wth + 6 * WP, wtl + 6 * WP, bo2, out, nullptr, 1};
    gemmN<OUT_F32, false, true, 1, 32, 2><<<dim3(8, 32, 2), gb, 0, stream>>>(j, jn, jn);
  }
}